// Round 6
// baseline (394.596 us; speedup 1.0000x reference)
//
#include <hip/hip_runtime.h>
#include <hip/hip_bf16.h>

typedef unsigned short ushort_t;
typedef __attribute__((ext_vector_type(8))) short bf16x8;   // 8 bf16 = 4 VGPRs
typedef __attribute__((ext_vector_type(4))) float f32x4;    // 4 fp32 acc

#define MDIM 2048
#define NDIM 4096

__device__ __forceinline__ ushort_t to_bf16(float f) {
    __hip_bfloat16 h = __float2bfloat16(f);
    return *reinterpret_cast<ushort_t*>(&h);
}

// ---------------- prep: fp32 -> bf16 cast ----------------
__global__ void cast_bf16_kernel(const float* __restrict__ in, ushort_t* __restrict__ out, int n) {
    int i = blockIdx.x * blockDim.x + threadIdx.x;
    if (i < n) out[i] = to_bf16(in[i]);
}

// ---------------- prep: W[K][N] fp32 -> fragment-major bf16 ----------------
// Frag (nblk, kblk) = 16 n-rows x 32 k, stored as 64 lanes x 8 elems (1KB
// contiguous): elem(l, e) = W[kblk*32 + (l>>4)*8 + e][nblk*16 + (l&15)].
// A wave's MFMA B-operand load becomes ONE coalesced 1KB global_load_dwordx4
// (v5's failure was 16-segment scattered loads: this fixes the transaction
// count, keeping bytes/order bitwise identical to the old LDS-staged path).
__global__ void pack_frag_kernel(const float* __restrict__ W, ushort_t* __restrict__ WF,
                                 int K, int N) {
    __shared__ float tile[32][33];
    const int tx = threadIdx.x, ty = threadIdx.y;  // (32, 8)
    const int n0 = blockIdx.x * 32, k0 = blockIdx.y * 32;
#pragma unroll
    for (int r = 0; r < 4; ++r)
        tile[ty + r * 8][tx] = W[(size_t)(k0 + ty + r * 8) * N + n0 + tx];
    __syncthreads();
    const int t  = ty * 32 + tx;    // 0..255
    const int s  = t >> 7;          // which nblk of the 2 in this 32n tile
    const int r2 = t & 127;
    const int l  = r2 >> 1;         // lane 0..63
    const int eh = (r2 & 1) * 4;    // elem half (0 or 4)
    const int nl = s * 16 + (l & 15);
    const int kl = (l >> 4) * 8 + eh;
    ushort4 o;
    o.x = to_bf16(tile[kl + 0][nl]);
    o.y = to_bf16(tile[kl + 1][nl]);
    o.z = to_bf16(tile[kl + 2][nl]);
    o.w = to_bf16(tile[kl + 3][nl]);
    const int KB = K >> 5;          // kblks per n-row of frags
    const size_t base = ((size_t)((n0 >> 4) + s) * KB + (k0 >> 5)) * 512 + l * 8 + eh;
    *reinterpret_cast<ushort4*>(&WF[base]) = o;   // threads write contiguous 8B
}

// ---------------- GEMM v7: A via LDS, B via fragment-major global loads ----------------
// C[M][N] = act(A[M][K] @ B + bias), B prepacked fragment-major.
// BM=128, BN=256, BK=64, 8 waves (2Mx4N), wave tile 64x64. Grid 16x16 = 1/CU.
// v4 (validated twice): tile = LDS-serve(1536) + MFMA(1240) exact SUM - the
// LDS port is the co-bottleneck. v6 (2 blocks/CU) phase-locked in-phase:
// regressed. v7 removes B from LDS: per-tile per-CU demand becomes
// MFMA 1240 (matrix pipe) | LDS ~900 (A only) | L2 ~1170 (B frags, 1-txn
// coalesced) - three different pipes that overlap.
// A path unchanged from v4: global_load_lds, 3 buffers, chunk-XOR swizzle
// (0 bank conflicts), distance-2 prefetch, counted vmcnt (never 0 mid-loop).
// B: 8 coalesced 1KB frag loads per wave per tile, distance-1 reg prefetch.
// Fragment bytes + MFMA order bitwise identical to v4 -> absmax unchanged.

#define GLD(gp, lp) __builtin_amdgcn_global_load_lds(                      \
        (const __attribute__((address_space(1))) void*)(gp),               \
        (__attribute__((address_space(3))) void*)(lp), 16, 0, 0)

#define MFMA(d, a, b) d = __builtin_amdgcn_mfma_f32_16x16x32_bf16(a, b, d, 0, 0, 0)

template <typename OutT, bool RELU>
__global__ __launch_bounds__(512, 2) void gemm_p8(const ushort_t* __restrict__ A,
                                                  const ushort_t* __restrict__ BF,
                                                  const float* __restrict__ bias,
                                                  OutT* __restrict__ C, int Kdim) {
    __shared__ __align__(16) ushort_t As[3][128 * 64];   // 48 KB total

    const int t = threadIdx.x;
    const int l = t & 63;
    const int w = t >> 6;          // wave 0..7
    const int l16 = l & 15;
    const int quad = l >> 4;
    const int wr = w >> 2;         // 0..1  (M)
    const int wc = w & 3;          // 0..3  (N)
    const int m0 = blockIdx.y * 128;
    const int n0 = blockIdx.x * 256;

    f32x4 acc[4][4];
#pragma unroll
    for (int i = 0; i < 4; ++i)
#pragma unroll
        for (int j = 0; j < 4; ++j) acc[i][j] = (f32x4){0.f, 0.f, 0.f, 0.f};

    // --- A staging addressing (v4-verified, conflict-free) ---
    const int srow = w * 8 + (l >> 3);
    const int scol = ((l & 7) ^ (l >> 3)) * 8;   // swizzled 16B chunk within the K-tile
    const ushort_t* gA0 = A + (size_t)(m0 + srow) * Kdim + scol;
    const ushort_t* gA1 = A + (size_t)(m0 + 64 + srow) * Kdim + scol;
    const int ldsW = w * 8 * 64;   // wave-uniform element offset of this wave's 8 rows

    // A fragment reads: row = wr*64 + i*16 + l16, chunk slot = (kk*4+quad)^(row&7)
    const int swz = l16 & 7;
#define LDA_(base, i, kk) (*(const bf16x8*)&(base)[(wr * 64 + (i) * 16 + l16) * 64 + ((((kk) * 4 + quad) ^ swz) * 8)])

    // B fragment pointers (fragment-major): frag(nblk, kb) is 1KB, lane-linear.
    const int KB = Kdim >> 5;      // kblks (K=32 each)
    const int nb0 = (n0 >> 4) + wc * 4;
    const ushort_t* pB0 = BF + (size_t)(nb0 + 0) * KB * 512 + l * 8;
    const ushort_t* pB1 = BF + (size_t)(nb0 + 1) * KB * 512 + l * 8;
    const ushort_t* pB2 = BF + (size_t)(nb0 + 2) * KB * 512 + l * 8;
    const ushort_t* pB3 = BF + (size_t)(nb0 + 3) * KB * 512 + l * 8;
#define BLF(p, kb) (*reinterpret_cast<const bf16x8*>((p) + (size_t)(kb) * 512))

#define STAGE_A(buf, koff) do {                         \
        GLD(gA0 + (koff), &As[buf][ldsW]);              \
        GLD(gA1 + (koff), &As[buf][ldsW + 64 * 64]);    \
    } while (0)

    // 16 MFMAs at one kk (i-major, j-minor -> per-acc order identical to prior versions)
#define MFMA16(a0, a1, a2, a3, b0, b1, b2, b3)                     \
        MFMA(acc[0][0], a0, b0); MFMA(acc[0][1], a0, b1);          \
        MFMA(acc[0][2], a0, b2); MFMA(acc[0][3], a0, b3);          \
        MFMA(acc[1][0], a1, b0); MFMA(acc[1][1], a1, b1);          \
        MFMA(acc[1][2], a1, b2); MFMA(acc[1][3], a1, b3);          \
        MFMA(acc[2][0], a2, b0); MFMA(acc[2][1], a2, b1);          \
        MFMA(acc[2][2], a2, b2); MFMA(acc[2][3], a2, b3);          \
        MFMA(acc[3][0], a3, b0); MFMA(acc[3][1], a3, b1);          \
        MFMA(acc[3][2], a3, b2); MFMA(acc[3][3], a3, b3)

    const int nt = Kdim >> 6;      // K-tiles of 64 (nt >= 4 for K in {256, 4096})

    // ---- prologue: GLD_A(0) < B(0) < GLD_A(1); vmcnt(2) keeps GLD_A(1) in flight ----
    STAGE_A(0, 0);
    __builtin_amdgcn_sched_barrier(0);
    bf16x8 bc00 = BLF(pB0, 0), bc01 = BLF(pB0, 1);
    bf16x8 bc10 = BLF(pB1, 0), bc11 = BLF(pB1, 1);
    bf16x8 bc20 = BLF(pB2, 0), bc21 = BLF(pB2, 1);
    bf16x8 bc30 = BLF(pB3, 0), bc31 = BLF(pB3, 1);
    __builtin_amdgcn_sched_barrier(0);
    STAGE_A(1, 64);
    asm volatile("s_waitcnt vmcnt(2)" ::: "memory");
    __builtin_amdgcn_s_barrier();

    for (int tt = 0; tt < nt; ++tt) {
        const int buf = tt % 3;
        const int nb = (tt + 2) % 3;
        const bool more = (tt + 2) < nt;

        const ushort_t* __restrict__ Ab = &As[buf][0];

        // A fragments of this K-tile from LDS (compiler emits counted lgkmcnt)
        bf16x8 a00 = LDA_(Ab, 0, 0), a01 = LDA_(Ab, 1, 0), a02 = LDA_(Ab, 2, 0), a03 = LDA_(Ab, 3, 0);
        bf16x8 a10 = LDA_(Ab, 0, 1), a11 = LDA_(Ab, 1, 1), a12 = LDA_(Ab, 2, 1), a13 = LDA_(Ab, 3, 1);

        // B fragments of tile tt+1: coalesced reg prefetch (issue BEFORE A GLDs)
        bf16x8 bn00, bn01, bn10, bn11, bn20, bn21, bn30, bn31;
        if (tt + 1 < nt) {
            const int kb = 2 * (tt + 1);
            bn00 = BLF(pB0, kb); bn01 = BLF(pB0, kb + 1);
            bn10 = BLF(pB1, kb); bn11 = BLF(pB1, kb + 1);
            bn20 = BLF(pB2, kb); bn21 = BLF(pB2, kb + 1);
            bn30 = BLF(pB3, kb); bn31 = BLF(pB3, kb + 1);
        }
        __builtin_amdgcn_sched_barrier(0);
        if (more) STAGE_A(nb, (tt + 2) << 6);
        __builtin_amdgcn_sched_barrier(0);

        // 32 MFMAs, single barrier-free region; B already in VGPRs
        MFMA16(a00, a01, a02, a03, bc00, bc10, bc20, bc30);
        MFMA16(a10, a11, a12, a13, bc01, bc11, bc21, bc31);

        if (tt + 1 < nt) {
            // drain B(tt+1) + GLD_A(tt+1) (older); keep GLD_A(tt+2) in flight
            if (more) asm volatile("s_waitcnt vmcnt(2)" ::: "memory");
            else      asm volatile("s_waitcnt vmcnt(0)" ::: "memory");
            __builtin_amdgcn_s_barrier();
            bc00 = bn00; bc01 = bn01; bc10 = bn10; bc11 = bn11;
            bc20 = bn20; bc21 = bn21; bc30 = bn30; bc31 = bn31;
        }
    }

    // epilogue: C/D layout col=lane&15, row=quad*4+reg (unchanged mapping)
#pragma unroll
    for (int i = 0; i < 4; ++i) {
#pragma unroll
        for (int r = 0; r < 4; ++r) {
            const int grow = m0 + wr * 64 + i * 16 + quad * 4 + r;
#pragma unroll
            for (int j = 0; j < 4; ++j) {
                const int gcol = n0 + wc * 64 + j * 16 + l16;
                float v = acc[i][j][r] + bias[gcol];
                if (RELU) v = fmaxf(v, 0.0f);
                if constexpr (sizeof(OutT) == 2) {
                    C[(size_t)grow * NDIM + gcol] = to_bf16(v);
                } else {
                    C[(size_t)grow * NDIM + gcol] = v;
                }
            }
        }
    }
}

// ---------------- Sinkhorn, factored: P = diag(a) K diag(b) ----------------
// (unchanged — register-resident K, readlane broadcast)
__device__ __forceinline__ float rdl(float v, int l) {
    return __uint_as_float(__builtin_amdgcn_readlane(__float_as_uint(v), l));
}

__global__ __launch_bounds__(64) void sinkhorn_kernel(float* __restrict__ PM) {
    __shared__ __align__(16) float T[64 * 65];  // one-time transpose staging
    const int l = threadIdx.x;
    float* base = PM + (size_t)blockIdx.x * 4096;

    float Kcol[64];  // Kcol[r] = K[r][l]  (column l)
    float Krow[64];  // Krow[c] = K[l][c]  (row l)
#pragma unroll
    for (int r = 0; r < 64; ++r)
        Kcol[r] = __expf(-base[r * 64 + l]);
#pragma unroll
    for (int r = 0; r < 64; ++r)
        T[r * 65 + l] = Kcol[r];
    __syncthreads();
#pragma unroll
    for (int c = 0; c < 64; ++c)
        Krow[c] = T[l * 65 + c];

    float a = 0.0f, b = 1.0f;
    for (int it = 0; it < 1000; ++it) {
        float t1 = 0.0f;  // (K b)_row=l
#pragma unroll
        for (int c = 0; c < 64; ++c)
            t1 = fmaf(Krow[c], rdl(b, c), t1);
        a = 0.015625f / t1;  // r = 1/64

        float t2 = 0.0f;  // (K^T a)_col=l
#pragma unroll
        for (int r = 0; r < 64; ++r)
            t2 = fmaf(Kcol[r], rdl(a, r), t2);
        const float err = fabsf(b * t2 - 0.015625f);
        if (__ballot(err > 1e-6f) == 0ull) break;
        b = 0.015625f / t2;
    }

#pragma unroll
    for (int r = 0; r < 64; ++r)
        base[r * 64 + l] = rdl(a, r) * Kcol[r] * b;
}

extern "C" void kernel_launch(void* const* d_in, const int* in_sizes, int n_in,
                              void* d_out, int out_size, void* d_ws, size_t ws_size,
                              hipStream_t stream) {
    const float* z  = (const float*)d_in[0];
    const float* W1 = (const float*)d_in[1];
    const float* b1 = (const float*)d_in[2];
    const float* W2 = (const float*)d_in[3];
    const float* b2 = (const float*)d_in[4];
    const float* W3 = (const float*)d_in[5];
    const float* b3 = (const float*)d_in[6];
    float* out = (float*)d_out;
    char* ws = (char*)d_ws;

    // workspace layout (bytes)
    ushort_t* W2F = (ushort_t*)(ws + 0);                       // 4096*4096*2 = 32 MB
    ushort_t* W3F = (ushort_t*)(ws + (size_t)33554432);        // 32 MB
    ushort_t* C1b = (ushort_t*)(ws + (size_t)67108864);        // 2048*4096*2 = 16 MB
    ushort_t* C2b = (ushort_t*)(ws + (size_t)83886080);        // 16 MB
    ushort_t* Zb  = (ushort_t*)(ws + (size_t)100663296);       // 2048*256*2 = 1 MB
    ushort_t* W1F = (ushort_t*)(ws + (size_t)101711872);       // 4096*256*2 = 2 MB

    // prep: cast z; pack weights fragment-major
    cast_bf16_kernel<<<2048, 256, 0, stream>>>(z, Zb, MDIM * 256);
    pack_frag_kernel<<<dim3(128, 8), dim3(32, 8), 0, stream>>>(W1, W1F, 256, 4096);
    pack_frag_kernel<<<dim3(128, 128), dim3(32, 8), 0, stream>>>(W2, W2F, 4096, 4096);
    pack_frag_kernel<<<dim3(128, 128), dim3(32, 8), 0, stream>>>(W3, W3F, 4096, 4096);

    // 3-layer MLP (bf16 MFMA, fp32 accum); layer 3 writes fp32 cost matrix into d_out
    gemm_p8<ushort_t, true><<<dim3(NDIM / 256, MDIM / 128), 512, 0, stream>>>(Zb, W1F, b1, C1b, 256);
    gemm_p8<ushort_t, true><<<dim3(NDIM / 256, MDIM / 128), 512, 0, stream>>>(C1b, W2F, b2, C2b, 4096);
    gemm_p8<float, false><<<dim3(NDIM / 256, MDIM / 128), 512, 0, stream>>>(C2b, W3F, b3, out, 4096);

    // Sinkhorn in-place on d_out (one wave per matrix, register-resident K)
    sinkhorn_kernel<<<2048, 64, 0, stream>>>(out);
}

// Round 7
// 338.771 us; speedup vs baseline: 1.1648x; 1.1648x over previous
//
#include <hip/hip_runtime.h>
#include <hip/hip_bf16.h>

typedef unsigned short ushort_t;
typedef __attribute__((ext_vector_type(8))) short bf16x8;   // 8 bf16 = 4 VGPRs
typedef __attribute__((ext_vector_type(4))) float f32x4;    // 4 fp32 acc

#define MDIM 2048
#define NDIM 4096

__device__ __forceinline__ ushort_t to_bf16(float f) {
    __hip_bfloat16 h = __float2bfloat16(f);
    return *reinterpret_cast<ushort_t*>(&h);
}

// ---------------- prep: fp32 -> bf16 cast ----------------
__global__ void cast_bf16_kernel(const float* __restrict__ in, ushort_t* __restrict__ out, int n) {
    int i = blockIdx.x * blockDim.x + threadIdx.x;
    if (i < n) out[i] = to_bf16(in[i]);
}

// ---------------- prep: W[K][N] fp32 -> WT[N][K] bf16 ----------------
__global__ void transpose_cast_kernel(const float* __restrict__ W, ushort_t* __restrict__ WT,
                                      int K, int N) {
    __shared__ float tile[32][33];
    const int tx = threadIdx.x, ty = threadIdx.y;  // (32, 8)
    const int n0 = blockIdx.x * 32, k0 = blockIdx.y * 32;
#pragma unroll
    for (int r = 0; r < 4; ++r)
        tile[ty + r * 8][tx] = W[(size_t)(k0 + ty + r * 8) * N + n0 + tx];
    __syncthreads();
    const int t = ty * 32 + tx;
    const int nl = t >> 3;          // 0..31 : local n
    const int kc = (t & 7) * 4;     // 0..28 : k chunk of 4
    ushort4 o;
    o.x = to_bf16(tile[kc + 0][nl]);
    o.y = to_bf16(tile[kc + 1][nl]);
    o.z = to_bf16(tile[kc + 2][nl]);
    o.w = to_bf16(tile[kc + 3][nl]);
    *reinterpret_cast<ushort4*>(&WT[(size_t)(n0 + nl) * K + k0 + kc]) = o;
}

// ---------------- GEMM v8: v4 structure + counted lgkmcnt split ----------------
// C[M][N] = act(A[M][K] @ BT[N][K]^T + bias)
// BM=128, BN=256, BK=64, 8 waves (2Mx4N), wave tile 64x64. Grid 16x16 = 1/CU.
// v5/v6/v7 post-mortem: every B-bypass-LDS variant regressed (latency /
// phase-lock). v4 (74us) is the validated base: A+B via global_load_lds,
// 3 buffers, chunk-XOR swizzle (0 conflicts), counted vmcnt(6), 1 barrier/tile.
// v4 residual: tile = port(1536) + MFMA(1240) exact SUM. Port math says kk0
// data is ready at ~768 (round-robin service of the 128-read queue), so
// MFMA(kk0) could overlap kk1's port service -> ~2150. The missing overlap is
// a drain-to-0 before the first MFMA (m218 signature, lgkm counter). v8 pins
// it at source: reads-kk0 | fence | reads-kk1 | fence | STAGE | fence |
// lgkmcnt(8) | fence | 16 MFMA kk0 | fence | lgkmcnt(0) | fence | 16 MFMA kk1.
// (rule #18: sched_barrier(0) immediately after each inline-asm waitcnt.)
// Data path + MFMA order unchanged -> numerics bitwise identical to v4.

#define GLD(gp, lp) __builtin_amdgcn_global_load_lds(                      \
        (const __attribute__((address_space(1))) void*)(gp),               \
        (__attribute__((address_space(3))) void*)(lp), 16, 0, 0)

#define MFMA(d, a, b) d = __builtin_amdgcn_mfma_f32_16x16x32_bf16(a, b, d, 0, 0, 0)

template <typename OutT, bool RELU>
__global__ __launch_bounds__(512, 2) void gemm_p8(const ushort_t* __restrict__ A,
                                                  const ushort_t* __restrict__ BT,
                                                  const float* __restrict__ bias,
                                                  OutT* __restrict__ C, int Kdim) {
    __shared__ __align__(16) ushort_t As[3][128 * 64];   // 48 KB
    __shared__ __align__(16) ushort_t Bs[3][256 * 64];   // 96 KB

    const int t = threadIdx.x;
    const int l = t & 63;
    const int w = t >> 6;          // wave 0..7
    const int l16 = l & 15;
    const int quad = l >> 4;
    const int wr = w >> 2;         // 0..1  (M)
    const int wc = w & 3;          // 0..3  (N)
    const int m0 = blockIdx.y * 128;
    const int n0 = blockIdx.x * 256;

    f32x4 acc[4][4];
#pragma unroll
    for (int i = 0; i < 4; ++i)
#pragma unroll
        for (int j = 0; j < 4; ++j) acc[i][j] = (f32x4){0.f, 0.f, 0.f, 0.f};

    // --- staging addressing (chunk-XOR swizzle, verified conflict-free) ---
    const int srow = w * 8 + (l >> 3);
    const int scol = ((l & 7) ^ (l >> 3)) * 8;   // swizzled 16B chunk within the K-tile
    const ushort_t* gA0 = A  + (size_t)(m0 + srow) * Kdim + scol;
    const ushort_t* gA1 = A  + (size_t)(m0 + 64 + srow) * Kdim + scol;
    const ushort_t* gB0 = BT + (size_t)(n0 + srow) * Kdim + scol;
    const ushort_t* gB1 = BT + (size_t)(n0 + 64 + srow) * Kdim + scol;
    const ushort_t* gB2 = BT + (size_t)(n0 + 128 + srow) * Kdim + scol;
    const ushort_t* gB3 = BT + (size_t)(n0 + 192 + srow) * Kdim + scol;
    const int ldsW = w * 8 * 64;   // wave-uniform element offset of this wave's 8 rows

    // fragment reads: row = (wtile + i*16 + l16), chunk slot = (kk*4+quad)^(row&7)
    const int swz = l16 & 7;       // == row&7 for all our fragment rows
#define LDA_(base, i, kk) (*(const bf16x8*)&(base)[(wr * 64 + (i) * 16 + l16) * 64 + ((((kk) * 4 + quad) ^ swz) * 8)])
#define LDB_(base, j, kk) (*(const bf16x8*)&(base)[(wc * 64 + (j) * 16 + l16) * 64 + ((((kk) * 4 + quad) ^ swz) * 8)])

#define STAGE_TILE(buf, koff) do {                      \
        GLD(gA0 + (koff), &As[buf][ldsW]);              \
        GLD(gA1 + (koff), &As[buf][ldsW + 64 * 64]);    \
        GLD(gB0 + (koff), &Bs[buf][ldsW]);              \
        GLD(gB1 + (koff), &Bs[buf][ldsW + 64 * 64]);    \
        GLD(gB2 + (koff), &Bs[buf][ldsW + 128 * 64]);   \
        GLD(gB3 + (koff), &Bs[buf][ldsW + 192 * 64]);   \
    } while (0)

    // 16 MFMAs at one kk (i-major, j-minor -> per-acc order identical to prior versions)
#define MFMA16(a0, a1, a2, a3, b0, b1, b2, b3)                     \
        MFMA(acc[0][0], a0, b0); MFMA(acc[0][1], a0, b1);          \
        MFMA(acc[0][2], a0, b2); MFMA(acc[0][3], a0, b3);          \
        MFMA(acc[1][0], a1, b0); MFMA(acc[1][1], a1, b1);          \
        MFMA(acc[1][2], a1, b2); MFMA(acc[1][3], a1, b3);          \
        MFMA(acc[2][0], a2, b0); MFMA(acc[2][1], a2, b1);          \
        MFMA(acc[2][2], a2, b2); MFMA(acc[2][3], a2, b3);          \
        MFMA(acc[3][0], a3, b0); MFMA(acc[3][1], a3, b1);          \
        MFMA(acc[3][2], a3, b2); MFMA(acc[3][3], a3, b3)

    const int nt = Kdim >> 6;      // K-tiles of 64 (nt >= 2 for K in {256, 4096})

    // prologue: stage tiles 0 and 1; wait tile 0 (6 newer outstanding), sync.
    STAGE_TILE(0, 0);
    STAGE_TILE(1, 64);
    asm volatile("s_waitcnt vmcnt(6)" ::: "memory");
    __builtin_amdgcn_s_barrier();

    for (int tt = 0; tt < nt; ++tt) {
        const int buf = tt % 3;
        const int nb = (tt + 2) % 3;
        const int koff = (tt + 2) << 6;
        const bool more = (tt + 2) < nt;

        const ushort_t* __restrict__ Ab = &As[buf][0];
        const ushort_t* __restrict__ Bb = &Bs[buf][0];

        // --- reads group kk=0 (issued FIRST: lgkmcnt(8) below waits on these) ---
        bf16x8 a00 = LDA_(Ab, 0, 0), a01 = LDA_(Ab, 1, 0), a02 = LDA_(Ab, 2, 0), a03 = LDA_(Ab, 3, 0);
        bf16x8 b00 = LDB_(Bb, 0, 0), b01 = LDB_(Bb, 1, 0), b02 = LDB_(Bb, 2, 0), b03 = LDB_(Bb, 3, 0);
        __builtin_amdgcn_sched_barrier(0);
        // --- reads group kk=1 ---
        bf16x8 a10 = LDA_(Ab, 0, 1), a11 = LDA_(Ab, 1, 1), a12 = LDA_(Ab, 2, 1), a13 = LDA_(Ab, 3, 1);
        bf16x8 b10 = LDB_(Bb, 0, 1), b11 = LDB_(Bb, 1, 1), b12 = LDB_(Bb, 2, 1), b13 = LDB_(Bb, 3, 1);
        __builtin_amdgcn_sched_barrier(0);

        // stage tile tt+2 (vmcnt-counted; in flight ~2 tile-times)
        if (more) STAGE_TILE(nb, koff);
        __builtin_amdgcn_sched_barrier(0);

        // wait only for the kk=0 group (8 newer = kk=1 group still outstanding)
        asm volatile("s_waitcnt lgkmcnt(8)" ::: "memory");
        __builtin_amdgcn_sched_barrier(0);
        MFMA16(a00, a01, a02, a03, b00, b01, b02, b03);
        __builtin_amdgcn_sched_barrier(0);
        asm volatile("s_waitcnt lgkmcnt(0)" ::: "memory");
        __builtin_amdgcn_sched_barrier(0);
        MFMA16(a10, a11, a12, a13, b10, b11, b12, b13);

        if (tt + 1 < nt) {
            // next iter reads buf (tt+1)%3: its 6 loads must be done. Newer in
            // flight = tile tt+2's 6 iff staged this iter -> vmcnt(6), else drain.
            if (more) asm volatile("s_waitcnt vmcnt(6)" ::: "memory");
            else      asm volatile("s_waitcnt vmcnt(0)" ::: "memory");
            __builtin_amdgcn_s_barrier();
        }
    }

    // epilogue: C/D layout col=lane&15, row=quad*4+reg (unchanged mapping)
#pragma unroll
    for (int i = 0; i < 4; ++i) {
#pragma unroll
        for (int r = 0; r < 4; ++r) {
            const int grow = m0 + wr * 64 + i * 16 + quad * 4 + r;
#pragma unroll
            for (int j = 0; j < 4; ++j) {
                const int gcol = n0 + wc * 64 + j * 16 + l16;
                float v = acc[i][j][r] + bias[gcol];
                if (RELU) v = fmaxf(v, 0.0f);
                if constexpr (sizeof(OutT) == 2) {
                    C[(size_t)grow * NDIM + gcol] = to_bf16(v);
                } else {
                    C[(size_t)grow * NDIM + gcol] = v;
                }
            }
        }
    }
}

// ---------------- Sinkhorn v2: LDS-broadcast matvec ----------------
// One wave per matrix; K register-resident both ways (Krow/Kcol).
// The readlane broadcast (64 v_readlane + 64 v_fma per matvec) is replaced by
// an LDS broadcast: write the 64-vector once (vec[l]=x), lgkmcnt(0), then
// 16 x ds_read_b128 with ALL lanes at the same address (broadcast, conflict-
// free) -> 80 inst/matvec instead of 128. 4-way split accumulators (sum
// reorder ~1e-7 relative: far below tolerance). Single wave: explicit
// lgkmcnt(0)+sched_barrier instead of __syncthreads (rule #18).
// Semantics vs reference unchanged: a <- r/(K b); err=max|b*(K^T a) - c|,
// break BEFORE b update; P = diag(a) K diag(b).
__global__ __launch_bounds__(64) void sinkhorn_kernel(float* __restrict__ PM) {
    __shared__ __align__(16) float T[64 * 65];  // one-time transpose staging
    __shared__ __align__(16) float vecA[64];
    __shared__ __align__(16) float vecB[64];
    const int l = threadIdx.x;
    float* base = PM + (size_t)blockIdx.x * 4096;

    float Kcol[64];  // Kcol[r] = K[r][l]  (column l)
    float Krow[64];  // Krow[c] = K[l][c]  (row l)
#pragma unroll
    for (int r = 0; r < 64; ++r)
        Kcol[r] = __expf(-base[r * 64 + l]);  // global /sum cancels in 1st row-norm
#pragma unroll
    for (int r = 0; r < 64; ++r)
        T[r * 65 + l] = Kcol[r];
    __syncthreads();
#pragma unroll
    for (int c = 0; c < 64; ++c)
        Krow[c] = T[l * 65 + c];  // stride-65: 2-way bank alias (free)

    const float4* __restrict__ vA4 = reinterpret_cast<const float4*>(vecA);
    const float4* __restrict__ vB4 = reinterpret_cast<const float4*>(vecB);

    float a = 0.0f, b = 1.0f;
    for (int it = 0; it < 1000; ++it) {
        // ---- t1 = (K b)_row=l ----
        vecB[l] = b;
        asm volatile("s_waitcnt lgkmcnt(0)" ::: "memory");
        __builtin_amdgcn_sched_barrier(0);
        float s0 = 0.f, s1 = 0.f, s2 = 0.f, s3 = 0.f;
#pragma unroll
        for (int q = 0; q < 16; ++q) {
            const float4 v = vB4[q];   // broadcast ds_read_b128
            s0 = fmaf(Krow[4 * q + 0], v.x, s0);
            s1 = fmaf(Krow[4 * q + 1], v.y, s1);
            s2 = fmaf(Krow[4 * q + 2], v.z, s2);
            s3 = fmaf(Krow[4 * q + 3], v.w, s3);
        }
        const float t1 = (s0 + s1) + (s2 + s3);
        a = 0.015625f / t1;  // r = 1/64

        // ---- t2 = (K^T a)_col=l ----
        vecA[l] = a;
        asm volatile("s_waitcnt lgkmcnt(0)" ::: "memory");
        __builtin_amdgcn_sched_barrier(0);
        float u0 = 0.f, u1 = 0.f, u2 = 0.f, u3 = 0.f;
#pragma unroll
        for (int q = 0; q < 16; ++q) {
            const float4 v = vA4[q];
            u0 = fmaf(Kcol[4 * q + 0], v.x, u0);
            u1 = fmaf(Kcol[4 * q + 1], v.y, u1);
            u2 = fmaf(Kcol[4 * q + 2], v.z, u2);
            u3 = fmaf(Kcol[4 * q + 3], v.w, u3);
        }
        const float t2 = (u0 + u1) + (u2 + u3);
        const float err = fabsf(b * t2 - 0.015625f);  // beta_c - c
        if (__ballot(err > 1e-6f) == 0ull) break;     // max over lanes <= eps
        b = 0.015625f / t2;
    }

    // writeback: P[r][l] = a_r * K[r][l] * b_l ; a_r via the LDS broadcast
    asm volatile("s_waitcnt lgkmcnt(0)" ::: "memory");
    __builtin_amdgcn_sched_barrier(0);
#pragma unroll
    for (int q = 0; q < 16; ++q) {
        const float4 av = vA4[q];
        base[(4 * q + 0) * 64 + l] = av.x * Kcol[4 * q + 0] * b;
        base[(4 * q + 1) * 64 + l] = av.y * Kcol[4 * q + 1] * b;
        base[(4 * q + 2) * 64 + l] = av.z * Kcol[4 * q + 2] * b;
        base[(4 * q + 3) * 64 + l] = av.w * Kcol[4 * q + 3] * b;
    }
}

extern "C" void kernel_launch(void* const* d_in, const int* in_sizes, int n_in,
                              void* d_out, int out_size, void* d_ws, size_t ws_size,
                              hipStream_t stream) {
    const float* z  = (const float*)d_in[0];
    const float* W1 = (const float*)d_in[1];
    const float* b1 = (const float*)d_in[2];
    const float* W2 = (const float*)d_in[3];
    const float* b2 = (const float*)d_in[4];
    const float* W3 = (const float*)d_in[5];
    const float* b3 = (const float*)d_in[6];
    float* out = (float*)d_out;
    char* ws = (char*)d_ws;

    // workspace layout (bytes)
    ushort_t* W2T = (ushort_t*)(ws + 0);                       // 4096*4096*2 = 32 MB
    ushort_t* W3T = (ushort_t*)(ws + (size_t)33554432);        // 32 MB
    ushort_t* C1b = (ushort_t*)(ws + (size_t)67108864);        // 2048*4096*2 = 16 MB
    ushort_t* C2b = (ushort_t*)(ws + (size_t)83886080);        // 16 MB
    ushort_t* Zb  = (ushort_t*)(ws + (size_t)100663296);       // 2048*256*2 = 1 MB
    ushort_t* W1T = (ushort_t*)(ws + (size_t)101711872);       // 4096*256*2 = 2 MB

    // prep
    cast_bf16_kernel<<<2048, 256, 0, stream>>>(z, Zb, MDIM * 256);
    transpose_cast_kernel<<<dim3(128, 8), dim3(32, 8), 0, stream>>>(W1, W1T, 256, 4096);
    transpose_cast_kernel<<<dim3(128, 128), dim3(32, 8), 0, stream>>>(W2, W2T, 4096, 4096);
    transpose_cast_kernel<<<dim3(128, 128), dim3(32, 8), 0, stream>>>(W3, W3T, 4096, 4096);

    // 3-layer MLP (bf16 MFMA, fp32 accum); layer 3 writes fp32 cost matrix into d_out
    gemm_p8<ushort_t, true><<<dim3(NDIM / 256, MDIM / 128), 512, 0, stream>>>(Zb, W1T, b1, C1b, 256);
    gemm_p8<ushort_t, true><<<dim3(NDIM / 256, MDIM / 128), 512, 0, stream>>>(C1b, W2T, b2, C2b, 4096);
    gemm_p8<float, false><<<dim3(NDIM / 256, MDIM / 128), 512, 0, stream>>>(C2b, W3T, b3, out, 4096);

    // Sinkhorn in-place on d_out (one wave per matrix, register-resident K)
    sinkhorn_kernel<<<2048, 64, 0, stream>>>(out);
}